// Round 12
// baseline (300.657 us; speedup 1.0000x reference)
//
#include <hip/hip_runtime.h>
#include <hip/hip_bf16.h>

#define N_NODES 100000
#define N_EDGES 3200000
#define N_GRAPHS 256

#define NBUCK 391                 // ceil(N_NODES / 256) coarse buckets (col >> 8)
#define SORT_ITEMS 8192           // edges per block in hist/scatter passes
#define NB_SORT ((N_EDGES + SORT_ITEMS - 1) / SORT_ITEMS)   // 391
#define HIST_N (NBUCK * NB_SORT)  // 152,881
#define ROW_MASK 131071           // 2^17 - 1 (N_NODES < 2^17)

__device__ __forceinline__ float bfl(int d) {  // low bf16 of dword -> f32
    return __uint_as_float(((unsigned)d) << 16);
}
__device__ __forceinline__ float bfh(int d) {  // high bf16 of dword -> f32
    return __uint_as_float(((unsigned)d) & 0xffff0000u);
}
__device__ __forceinline__ unsigned short f2bf(float f) {
    __hip_bfloat16 b = __float2bfloat16(f);
    return *(unsigned short*)&b;
}
__device__ __forceinline__ unsigned pack2bf(float lo, float hi) {
    return (unsigned)f2bf(lo) | ((unsigned)f2bf(hi) << 16);
}

// ---------------- pass 1: per-block histogram of coarse bucket (512 thr) ----------------
__global__ __launch_bounds__(512) void hist_kernel(const int* __restrict__ col,
                                                   int* __restrict__ hist) {
    __shared__ int h[NBUCK];
    int tid = threadIdx.x;
    for (int i = tid; i < NBUCK; i += 512) h[i] = 0;
    __syncthreads();
    int base = blockIdx.x * SORT_ITEMS + tid * 4;
    #pragma unroll
    for (int l = 0; l < SORT_ITEMS / 2048; ++l) {
        int e = base + l * 2048;
        if (e < N_EDGES) {
            int4 c4 = *(const int4*)&col[e];
            atomicAdd(&h[c4.x >> 8], 1);
            atomicAdd(&h[c4.y >> 8], 1);
            atomicAdd(&h[c4.z >> 8], 1);
            atomicAdd(&h[c4.w >> 8], 1);
        }
    }
    __syncthreads();
    for (int i = tid; i < NBUCK; i += 512) hist[i * NB_SORT + blockIdx.x] = h[i];
}

// ---------------- scan of hist (block-local): 4096/block ----------------
__global__ __launch_bounds__(256) void scanA_kernel(int* __restrict__ a,
                                                    int* __restrict__ bsum, int n) {
    __shared__ int s[256];
    int tid = threadIdx.x;
    int base = blockIdx.x * 4096 + tid * 16;
    int v[16];
    int sum = 0;
    #pragma unroll
    for (int i = 0; i < 16; ++i) { v[i] = (base + i < n) ? a[base + i] : 0; sum += v[i]; }
    s[tid] = sum;
    __syncthreads();
    for (int d = 1; d < 256; d <<= 1) {
        int x = (tid >= d) ? s[tid - d] : 0;
        __syncthreads();
        s[tid] += x;
        __syncthreads();
    }
    int run = s[tid] - sum;
    #pragma unroll
    for (int i = 0; i < 16; ++i) {
        if (base + i < n) a[base + i] = run;
        run += v[i];
    }
    if (tid == 255) bsum[blockIdx.x] = s[255];
}

__global__ __launch_bounds__(256) void scanB_kernel(int* bsum, int nb) {
    __shared__ int s[256];
    int tid = threadIdx.x;
    int v = (tid < nb) ? bsum[tid] : 0;
    s[tid] = v;
    __syncthreads();
    for (int d = 1; d < 256; d <<= 1) {
        int x = (tid >= d) ? s[tid - d] : 0;
        __syncthreads();
        s[tid] += x;
        __syncthreads();
    }
    if (tid < nb) bsum[tid] = s[tid] - v;  // exclusive
}

// ---------------- pass 2: scatter edges into coarse-bucket regions (512 thr) ----------------
// rw2 entry: { row | (col&255)<<17 , ew }
__global__ __launch_bounds__(512) void scatter_sort_kernel(const int* __restrict__ col,
                                                           const int* __restrict__ row,
                                                           const float* __restrict__ ew,
                                                           const int* __restrict__ hist,
                                                           const int* __restrict__ bsum,
                                                           int2* __restrict__ rw2) {
    __shared__ int offs[NBUCK];
    int tid = threadIdx.x;
    for (int i = tid; i < NBUCK; i += 512) {
        int idx = i * NB_SORT + blockIdx.x;
        offs[i] = hist[idx] + bsum[idx >> 12];
    }
    __syncthreads();
    int base = blockIdx.x * SORT_ITEMS + tid * 4;
    #pragma unroll
    for (int l = 0; l < SORT_ITEMS / 2048; ++l) {
        int e = base + l * 2048;
        if (e < N_EDGES) {
            int4 c4 = *(const int4*)&col[e];
            int4 r4 = *(const int4*)&row[e];
            float4 w4 = *(const float4*)&ew[e];
            int p0 = atomicAdd(&offs[c4.x >> 8], 1);
            int p1 = atomicAdd(&offs[c4.y >> 8], 1);
            int p2 = atomicAdd(&offs[c4.z >> 8], 1);
            int p3 = atomicAdd(&offs[c4.w >> 8], 1);
            int2 v0; v0.x = r4.x | ((c4.x & 255) << 17); v0.y = __float_as_int(w4.x);
            int2 v1; v1.x = r4.y | ((c4.y & 255) << 17); v1.y = __float_as_int(w4.y);
            int2 v2; v2.x = r4.z | ((c4.z & 255) << 17); v2.y = __float_as_int(w4.z);
            int2 v3; v3.x = r4.w | ((c4.w & 255) << 17); v3.y = __float_as_int(w4.w);
            rw2[p0] = v0;
            rw2[p1] = v1;
            rw2[p2] = v2;
            rw2[p3] = v3;
        }
    }
}

// ---------------- pass 3: per-bucket CSR build + deg/dinv (512 thr) ----------------
__global__ __launch_bounds__(512) void build_kernel(const int* __restrict__ hist,
                                                    const int* __restrict__ bsum,
                                                    const int2* __restrict__ rw2,
                                                    int* __restrict__ off,
                                                    int* __restrict__ cnt,
                                                    float* __restrict__ dinv,
                                                    int2* __restrict__ csr) {
    int b = blockIdx.x;
    int tid = threadIdx.x;
    int ib = b * NB_SORT;
    int begin = hist[ib] + bsum[ib >> 12];
    int end = N_EDGES;
    if (b + 1 < NBUCK) {
        int ie = (b + 1) * NB_SORT;
        end = hist[ie] + bsum[ie >> 12];
    }
    __shared__ int lcnt[256];
    __shared__ float ldeg[256];
    __shared__ int s[512];
    __shared__ int curo[256];
    if (tid < 256) { lcnt[tid] = 0; ldeg[tid] = 0.f; }
    __syncthreads();
    for (int e = begin + tid; e < end; e += 2048) {
        int2 a0 = rw2[e];
        int e1 = e + 512, e2 = e + 1024, e3 = e + 1536;
        int2 a1 = (e1 < end) ? rw2[e1] : make_int2(0, 0);
        int2 a2 = (e2 < end) ? rw2[e2] : make_int2(0, 0);
        int2 a3 = (e3 < end) ? rw2[e3] : make_int2(0, 0);
        atomicAdd(&lcnt[a0.x >> 17], 1);
        atomicAdd(&ldeg[a0.x >> 17], __int_as_float(a0.y));
        if (e1 < end) { atomicAdd(&lcnt[a1.x >> 17], 1); atomicAdd(&ldeg[a1.x >> 17], __int_as_float(a1.y)); }
        if (e2 < end) { atomicAdd(&lcnt[a2.x >> 17], 1); atomicAdd(&ldeg[a2.x >> 17], __int_as_float(a2.y)); }
        if (e3 < end) { atomicAdd(&lcnt[a3.x >> 17], 1); atomicAdd(&ldeg[a3.x >> 17], __int_as_float(a3.y)); }
    }
    __syncthreads();
    int v = (tid < 256) ? lcnt[tid] : 0;
    s[tid] = v;
    __syncthreads();
    for (int d = 1; d < 512; d <<= 1) {
        int x = (tid >= d) ? s[tid - d] : 0;
        __syncthreads();
        s[tid] += x;
        __syncthreads();
    }
    if (tid < 256) {
        int excl = s[tid] - v;
        int node = (b << 8) + tid;
        if (node < N_NODES) {
            off[node] = begin + excl;
            cnt[node] = v;
            dinv[node] = rsqrtf(1.0f + ldeg[tid]);
        }
        curo[tid] = begin + excl;
    }
    __syncthreads();
    for (int e = begin + tid; e < end; e += 2048) {
        int2 a0 = rw2[e];
        int e1 = e + 512, e2 = e + 1024, e3 = e + 1536;
        int2 a1 = (e1 < end) ? rw2[e1] : make_int2(0, 0);
        int2 a2 = (e2 < end) ? rw2[e2] : make_int2(0, 0);
        int2 a3 = (e3 < end) ? rw2[e3] : make_int2(0, 0);
        int p0 = atomicAdd(&curo[a0.x >> 17], 1);
        csr[p0] = make_int2(a0.x & ROW_MASK, a0.y);
        if (e1 < end) { int p = atomicAdd(&curo[a1.x >> 17], 1); csr[p] = make_int2(a1.x & ROW_MASK, a1.y); }
        if (e2 < end) { int p = atomicAdd(&curo[a2.x >> 17], 1); csr[p] = make_int2(a2.x & ROW_MASK, a2.y); }
        if (e3 < end) { int p = atomicAdd(&curo[a3.x >> 17], 1); csr[p] = make_int2(a3.x & ROW_MASK, a3.y); }
    }
}

// ------- tiled f32-input GEMM, bf16 output: H = bf16((X@W)*scale) -------
template <int IN, int OUT, int ROWS>
__global__ __launch_bounds__(256) void gemm_bf16_kernel(const float* __restrict__ X,
                                                        const float* __restrict__ W,
                                                        const float* __restrict__ scale,
                                                        unsigned short* __restrict__ H, int n) {
    constexpr int BK = 16;
    constexpr int TX = OUT / 4;
    constexpr int TY = ROWS / 8;
    static_assert(TX * TY == 256, "block must be 256 threads");
    __shared__ float xsT[BK][ROWS + 4];
    __shared__ float ws[BK][OUT + 4];
    int tid = threadIdx.x;
    int tx = tid % TX, ty = tid / TX;
    int r0 = blockIdx.x * ROWS;
    float acc[8][4] = {};
    for (int k0 = 0; k0 < IN; k0 += BK) {
        constexpr int XL = (ROWS * BK) / (256 * 4);
        #pragma unroll
        for (int l = 0; l < XL; ++l) {
            int t = tid + l * 256;
            int rr = t >> 2;
            int kp = (t & 3) * 4;
            float4 v = make_float4(0.f, 0.f, 0.f, 0.f);
            int gr = r0 + rr;
            if (gr < n) v = *(const float4*)&X[(size_t)gr * IN + k0 + kp];
            xsT[kp + 0][rr] = v.x;
            xsT[kp + 1][rr] = v.y;
            xsT[kp + 2][rr] = v.z;
            xsT[kp + 3][rr] = v.w;
        }
        constexpr int WL = (BK * OUT) / 4;
        if (WL == 256 || tid < WL) {
            int kr = tid / TX;
            int cp = (tid % TX) * 4;
            float4 v = *(const float4*)&W[(size_t)(k0 + kr) * OUT + cp];
            *(float4*)&ws[kr][cp] = v;
        }
        __syncthreads();
        #pragma unroll
        for (int kk = 0; kk < BK; ++kk) {
            float4 a0 = *(const float4*)&xsT[kk][ty * 8];
            float4 a1 = *(const float4*)&xsT[kk][ty * 8 + 4];
            float4 b = *(const float4*)&ws[kk][tx * 4];
            float av[8] = {a0.x, a0.y, a0.z, a0.w, a1.x, a1.y, a1.z, a1.w};
            float bv[4] = {b.x, b.y, b.z, b.w};
            #pragma unroll
            for (int i = 0; i < 8; ++i) {
                #pragma unroll
                for (int j = 0; j < 4; ++j) acc[i][j] = fmaf(av[i], bv[j], acc[i][j]);
            }
        }
        __syncthreads();
    }
    #pragma unroll
    for (int i = 0; i < 8; ++i) {
        int gr = r0 + ty * 8 + i;
        if (gr < n) {
            float sc = scale[gr];
            ushort4 o;
            o.x = f2bf(acc[i][0] * sc);
            o.y = f2bf(acc[i][1] * sc);
            o.z = f2bf(acc[i][2] * sc);
            o.w = f2bf(acc[i][3] * sc);
            *(ushort4*)&H[(size_t)gr * OUT + tx * 4] = o;
        }
    }
}

// ---------------- fused agg1 + gemm2: wave per node ----------------
// Phase A (agg): 8 edge-slots x 8 feat-blocks, shfl broadcast, bf16 gather.
// Phase B (fused conv2 linear): all lanes hold the h1p row after reduce;
// lane (es,fb) multiplies its 8 feats by its register-resident W2 block
// (8x4 for out-cols es*4..es*4+3), reduce over fb, write h2t = bf16(p*dinv).
__global__ __launch_bounds__(256) void agg1_kernel(const int2* __restrict__ csr,
                                                   const int* __restrict__ off,
                                                   const int* __restrict__ cnt,
                                                   const float* __restrict__ dinv,
                                                   const unsigned short* __restrict__ h1t,
                                                   const float* __restrict__ b1,
                                                   const float* __restrict__ W2g,
                                                   unsigned short* __restrict__ h2t) {
    int lane = threadIdx.x & 63;
    int node = blockIdx.x * 4 + (threadIdx.x >> 6);
    int es = lane >> 3;   // edge slot 0..7
    int fb = lane & 7;    // feat block 0..7 (8 feats each)
    // preload this lane's W2 block: rows fb*8..fb*8+7, cols es*4..es*4+3
    float w2r[8][4];
    #pragma unroll
    for (int i = 0; i < 8; ++i) {
        float4 t = *(const float4*)&W2g[(fb * 8 + i) * 32 + es * 4];
        w2r[i][0] = t.x; w2r[i][1] = t.y; w2r[i][2] = t.z; w2r[i][3] = t.w;
    }
    int s = off[node], c = cnt[node];
    float acc[8] = {};
    for (int j0 = 0; j0 < c; j0 += 64) {
        int m = min(64, c - j0);
        int2 e = make_int2(0, 0);
        if (lane < m) e = csr[s + j0 + lane];
        int ng = (m + 7) >> 3;
        int g = 0;
        for (; g + 2 <= ng; g += 2) {
            int s0 = g * 8 + es;
            int s1 = s0 + 8;
            int r0 = __shfl(e.x, s0);
            float w0 = __int_as_float(__shfl(e.y, s0));
            int r1 = __shfl(e.x, s1);
            float w1 = __int_as_float(__shfl(e.y, s1));
            int4 d0 = *(const int4*)(h1t + (((size_t)r0) << 6) + (fb << 3));
            int4 d1 = *(const int4*)(h1t + (((size_t)r1) << 6) + (fb << 3));
            acc[0] = fmaf(w0, bfl(d0.x), acc[0]);
            acc[1] = fmaf(w0, bfh(d0.x), acc[1]);
            acc[2] = fmaf(w0, bfl(d0.y), acc[2]);
            acc[3] = fmaf(w0, bfh(d0.y), acc[3]);
            acc[4] = fmaf(w0, bfl(d0.z), acc[4]);
            acc[5] = fmaf(w0, bfh(d0.z), acc[5]);
            acc[6] = fmaf(w0, bfl(d0.w), acc[6]);
            acc[7] = fmaf(w0, bfh(d0.w), acc[7]);
            acc[0] = fmaf(w1, bfl(d1.x), acc[0]);
            acc[1] = fmaf(w1, bfh(d1.x), acc[1]);
            acc[2] = fmaf(w1, bfl(d1.y), acc[2]);
            acc[3] = fmaf(w1, bfh(d1.y), acc[3]);
            acc[4] = fmaf(w1, bfl(d1.z), acc[4]);
            acc[5] = fmaf(w1, bfh(d1.z), acc[5]);
            acc[6] = fmaf(w1, bfl(d1.w), acc[6]);
            acc[7] = fmaf(w1, bfh(d1.w), acc[7]);
        }
        if (g < ng) {
            int s0 = g * 8 + es;
            int r0 = __shfl(e.x, s0);
            float w0 = __int_as_float(__shfl(e.y, s0));
            int4 d0 = *(const int4*)(h1t + (((size_t)r0) << 6) + (fb << 3));
            acc[0] = fmaf(w0, bfl(d0.x), acc[0]);
            acc[1] = fmaf(w0, bfh(d0.x), acc[1]);
            acc[2] = fmaf(w0, bfl(d0.y), acc[2]);
            acc[3] = fmaf(w0, bfh(d0.y), acc[3]);
            acc[4] = fmaf(w0, bfl(d0.z), acc[4]);
            acc[5] = fmaf(w0, bfh(d0.z), acc[5]);
            acc[6] = fmaf(w0, bfl(d0.w), acc[6]);
            acc[7] = fmaf(w0, bfh(d0.w), acc[7]);
        }
    }
    #pragma unroll
    for (int mask = 8; mask <= 32; mask <<= 1) {
        #pragma unroll
        for (int k = 0; k < 8; ++k) acc[k] += __shfl_xor(acc[k], mask);
    }
    // all lanes: finish h1p feats fb*8..fb*8+7 (bias + dinv + ReLU) in-register
    float di = dinv[node];
    int4 ds = *(const int4*)(h1t + (((size_t)node) << 6) + (fb << 3));
    float4 bv0 = *(const float4*)&b1[fb * 8];
    float4 bv1 = *(const float4*)&b1[fb * 8 + 4];
    float hp[8];
    hp[0] = fmaxf(fmaf(acc[0] + bfl(ds.x), di, bv0.x), 0.f);
    hp[1] = fmaxf(fmaf(acc[1] + bfh(ds.x), di, bv0.y), 0.f);
    hp[2] = fmaxf(fmaf(acc[2] + bfl(ds.y), di, bv0.z), 0.f);
    hp[3] = fmaxf(fmaf(acc[3] + bfh(ds.y), di, bv0.w), 0.f);
    hp[4] = fmaxf(fmaf(acc[4] + bfl(ds.z), di, bv1.x), 0.f);
    hp[5] = fmaxf(fmaf(acc[5] + bfh(ds.z), di, bv1.y), 0.f);
    hp[6] = fmaxf(fmaf(acc[6] + bfl(ds.w), di, bv1.z), 0.f);
    hp[7] = fmaxf(fmaf(acc[7] + bfh(ds.w), di, bv1.w), 0.f);
    // matvec partials for out-cols es*4..es*4+3 over this lane's 8 k values
    float p0 = 0.f, p1 = 0.f, p2 = 0.f, p3 = 0.f;
    #pragma unroll
    for (int i = 0; i < 8; ++i) {
        p0 = fmaf(hp[i], w2r[i][0], p0);
        p1 = fmaf(hp[i], w2r[i][1], p1);
        p2 = fmaf(hp[i], w2r[i][2], p2);
        p3 = fmaf(hp[i], w2r[i][3], p3);
    }
    // reduce over fb (lane bits 0..2)
    #pragma unroll
    for (int mask = 1; mask <= 4; mask <<= 1) {
        p0 += __shfl_xor(p0, mask);
        p1 += __shfl_xor(p1, mask);
        p2 += __shfl_xor(p2, mask);
        p3 += __shfl_xor(p3, mask);
    }
    if (fb == 0) {  // 8 lanes, es = 0..7 -> cols es*4..es*4+3
        unsigned lo = pack2bf(p0 * di, p1 * di);
        unsigned hi = pack2bf(p2 * di, p3 * di);
        *(int2*)(h2t + (((size_t)node) << 5) + (es << 2)) = make_int2((int)lo, (int)hi);
    }
}

// ---------------- aggregation conv2: 32 feats, half-wave per node ----------------
__global__ __launch_bounds__(256) void agg2_kernel(const int2* __restrict__ csr,
                                                   const int* __restrict__ off,
                                                   const int* __restrict__ cnt,
                                                   const float* __restrict__ dinv,
                                                   const unsigned short* __restrict__ h2t,
                                                   const float* __restrict__ b2,
                                                   float* __restrict__ h2p) {
    int lane = threadIdx.x & 63;
    int half = lane >> 5;
    int hl = lane & 31;
    int es = hl >> 2;   // edge slot 0..7
    int fb = hl & 3;    // feat block 0..3 (8 feats each)
    int wid = threadIdx.x >> 6;
    int node = blockIdx.x * 8 + wid * 2 + half;
    int s = off[node], c = cnt[node];
    int lbase = half << 5;
    float acc[8] = {};
    for (int j0 = 0; j0 < c; j0 += 32) {
        int m = min(32, c - j0);
        int2 e = make_int2(0, 0);
        if (hl < m) e = csr[s + j0 + hl];
        int ng = (m + 7) >> 3;
        int g = 0;
        for (; g + 2 <= ng; g += 2) {
            int s0 = lbase + g * 8 + es;
            int s1 = s0 + 8;
            int r0 = __shfl(e.x, s0);
            float w0 = __int_as_float(__shfl(e.y, s0));
            int r1 = __shfl(e.x, s1);
            float w1 = __int_as_float(__shfl(e.y, s1));
            int4 d0 = *(const int4*)(h2t + (((size_t)r0) << 5) + (fb << 3));
            int4 d1 = *(const int4*)(h2t + (((size_t)r1) << 5) + (fb << 3));
            acc[0] = fmaf(w0, bfl(d0.x), acc[0]);
            acc[1] = fmaf(w0, bfh(d0.x), acc[1]);
            acc[2] = fmaf(w0, bfl(d0.y), acc[2]);
            acc[3] = fmaf(w0, bfh(d0.y), acc[3]);
            acc[4] = fmaf(w0, bfl(d0.z), acc[4]);
            acc[5] = fmaf(w0, bfh(d0.z), acc[5]);
            acc[6] = fmaf(w0, bfl(d0.w), acc[6]);
            acc[7] = fmaf(w0, bfh(d0.w), acc[7]);
            acc[0] = fmaf(w1, bfl(d1.x), acc[0]);
            acc[1] = fmaf(w1, bfh(d1.x), acc[1]);
            acc[2] = fmaf(w1, bfl(d1.y), acc[2]);
            acc[3] = fmaf(w1, bfh(d1.y), acc[3]);
            acc[4] = fmaf(w1, bfl(d1.z), acc[4]);
            acc[5] = fmaf(w1, bfh(d1.z), acc[5]);
            acc[6] = fmaf(w1, bfl(d1.w), acc[6]);
            acc[7] = fmaf(w1, bfh(d1.w), acc[7]);
        }
        if (g < ng) {
            int s0 = lbase + g * 8 + es;
            int r0 = __shfl(e.x, s0);
            float w0 = __int_as_float(__shfl(e.y, s0));
            int4 d0 = *(const int4*)(h2t + (((size_t)r0) << 5) + (fb << 3));
            acc[0] = fmaf(w0, bfl(d0.x), acc[0]);
            acc[1] = fmaf(w0, bfh(d0.x), acc[1]);
            acc[2] = fmaf(w0, bfl(d0.y), acc[2]);
            acc[3] = fmaf(w0, bfh(d0.y), acc[3]);
            acc[4] = fmaf(w0, bfl(d0.z), acc[4]);
            acc[5] = fmaf(w0, bfh(d0.z), acc[5]);
            acc[6] = fmaf(w0, bfl(d0.w), acc[6]);
            acc[7] = fmaf(w0, bfh(d0.w), acc[7]);
        }
    }
    #pragma unroll
    for (int mask = 4; mask <= 16; mask <<= 1) {
        #pragma unroll
        for (int k = 0; k < 8; ++k) acc[k] += __shfl_xor(acc[k], mask);
    }
    if (es == 0) {  // hl 0..3; fb == hl
        float di = dinv[node];
        int4 ds = *(const int4*)(h2t + (((size_t)node) << 5) + (fb << 3));
        float4 bv0 = *(const float4*)&b2[fb * 8];
        float4 bv1 = *(const float4*)&b2[fb * 8 + 4];
        float4 o0, o1;
        o0.x = fmaf(acc[0] + bfl(ds.x), di, bv0.x);
        o0.y = fmaf(acc[1] + bfh(ds.x), di, bv0.y);
        o0.z = fmaf(acc[2] + bfl(ds.y), di, bv0.z);
        o0.w = fmaf(acc[3] + bfh(ds.y), di, bv0.w);
        o1.x = fmaf(acc[4] + bfl(ds.z), di, bv1.x);
        o1.y = fmaf(acc[5] + bfh(ds.z), di, bv1.y);
        o1.z = fmaf(acc[6] + bfl(ds.w), di, bv1.z);
        o1.w = fmaf(acc[7] + bfh(ds.w), di, bv1.w);
        float* po = h2p + (size_t)node * 32 + fb * 8;
        *(float4*)po = o0;
        *(float4*)(po + 4) = o1;
    }
}

// ---------------- fused pool + MLP head: one block per graph ----------------
__global__ __launch_bounds__(256) void pool_head_kernel(const float* __restrict__ h2p,
                                                        const int* __restrict__ batch,
                                                        const float* __restrict__ Wl1,
                                                        const float* __restrict__ bl1,
                                                        const float* __restrict__ Wl2,
                                                        const float* __restrict__ bl2,
                                                        float* __restrict__ out) {
    int g = blockIdx.x;
    int lo = 0, hi = N_NODES;
    while (lo < hi) { int m = (lo + hi) >> 1; if (batch[m] < g) lo = m + 1; else hi = m; }
    int start = lo;
    hi = N_NODES;
    while (lo < hi) { int m = (lo + hi) >> 1; if (batch[m] < g + 1) lo = m + 1; else hi = m; }
    int end = lo;
    int f = threadIdx.x & 31, grp = threadIdx.x >> 5;
    float acc = 0.f;
    for (int n = start + grp; n < end; n += 8) acc += h2p[(size_t)n * 32 + f];
    __shared__ float red[8][32];
    __shared__ float usum[32];
    red[grp][f] = acc;
    __syncthreads();
    if (threadIdx.x < 32) {
        float sum = 0.f;
        #pragma unroll
        for (int k = 0; k < 8; ++k) sum += red[k][threadIdx.x];
        usum[threadIdx.x] = sum;
    }
    __syncthreads();
    if (threadIdx.x < 16) {
        int j = threadIdx.x;
        float h = bl1[j];
        #pragma unroll
        for (int k = 0; k < 32; ++k) h = fmaf(usum[k], Wl1[k * 16 + j], h);
        float t = fmaxf(h, 0.f) * Wl2[j];
        t += __shfl_xor(t, 1);
        t += __shfl_xor(t, 2);
        t += __shfl_xor(t, 4);
        t += __shfl_xor(t, 8);
        if (j == 0) out[g] = t + bl2[0];
    }
}

extern "C" void kernel_launch(void* const* d_in, const int* in_sizes, int n_in,
                              void* d_out, int out_size, void* d_ws, size_t ws_size,
                              hipStream_t stream) {
    const float* x     = (const float*)d_in[0];
    const int*   ei    = (const int*)d_in[1];
    const float* ew    = (const float*)d_in[2];
    const int*   batch = (const int*)d_in[3];
    const float* W1    = (const float*)d_in[4];
    const float* b1    = (const float*)d_in[5];
    const float* W2    = (const float*)d_in[6];
    const float* b2    = (const float*)d_in[7];
    const float* Wl1   = (const float*)d_in[8];
    const float* bl1   = (const float*)d_in[9];
    const float* Wl2   = (const float*)d_in[10];
    const float* bl2   = (const float*)d_in[11];
    float* out = (float*)d_out;

    const int* row = ei;
    const int* col = ei + N_EDGES;

    char* p = (char*)d_ws;
    auto alloc = [&](size_t bytes) {
        char* q = p;
        p += (bytes + 255) & ~(size_t)255;
        return q;
    };
    int*   hist   = (int*)alloc((size_t)HIST_N * 4);
    int*   bsum   = (int*)alloc(1024 * 4);
    int2*  rw2    = (int2*)alloc((size_t)N_EDGES * 8);
    int*   off    = (int*)alloc(N_NODES * 4);
    int*   cnt    = (int*)alloc(N_NODES * 4);
    float* dinv   = (float*)alloc(N_NODES * 4);
    int2*  csr    = (int2*)alloc((size_t)N_EDGES * 8);
    unsigned short* h1t = (unsigned short*)rw2;  // alias: rw2 dead after build
    unsigned short* h2t = (unsigned short*)alloc((size_t)N_NODES * 32 * 2);
    float* h2p    = (float*)alloc((size_t)N_NODES * 32 * 4);

    const int nbScan = (HIST_N + 4095) / 4096;  // 38

    hist_kernel<<<NB_SORT, 512, 0, stream>>>(col, hist);
    scanA_kernel<<<nbScan, 256, 0, stream>>>(hist, bsum, HIST_N);
    scanB_kernel<<<1, 256, 0, stream>>>(bsum, nbScan);
    scatter_sort_kernel<<<NB_SORT, 512, 0, stream>>>(col, row, ew, hist, bsum, rw2);
    build_kernel<<<NBUCK, 512, 0, stream>>>(hist, bsum, rw2, off, cnt, dinv, csr);

    gemm_bf16_kernel<128, 64, 128><<<(N_NODES + 127) / 128, 256, 0, stream>>>(x, W1, dinv, h1t, N_NODES);
    agg1_kernel<<<N_NODES / 4, 256, 0, stream>>>(csr, off, cnt, dinv, h1t, b1, W2, h2t);
    agg2_kernel<<<N_NODES / 8, 256, 0, stream>>>(csr, off, cnt, dinv, h2t, b2, h2p);
    pool_head_kernel<<<N_GRAPHS, 256, 0, stream>>>(h2p, batch, Wl1, bl1, Wl2, bl2, out);
}

// Round 13
// 258.976 us; speedup vs baseline: 1.1609x; 1.1609x over previous
//
#include <hip/hip_runtime.h>
#include <hip/hip_bf16.h>

#define N_NODES 100000
#define N_EDGES 3200000
#define N_GRAPHS 256

#define NBUCK 391                 // ceil(N_NODES / 256) coarse buckets (col >> 8)
#define SORT_ITEMS 8192           // edges per block in hist/scatter passes
#define NB_SORT ((N_EDGES + SORT_ITEMS - 1) / SORT_ITEMS)   // 391
#define HIST_N (NBUCK * NB_SORT)  // 152,881
#define ROW_MASK 131071           // 2^17 - 1 (N_NODES < 2^17)

__device__ __forceinline__ float bfl(int d) {  // low bf16 of dword -> f32
    return __uint_as_float(((unsigned)d) << 16);
}
__device__ __forceinline__ float bfh(int d) {  // high bf16 of dword -> f32
    return __uint_as_float(((unsigned)d) & 0xffff0000u);
}
__device__ __forceinline__ unsigned short f2bf(float f) {
    __hip_bfloat16 b = __float2bfloat16(f);
    return *(unsigned short*)&b;
}
__device__ __forceinline__ unsigned pack2bf(float lo, float hi) {
    return (unsigned)f2bf(lo) | ((unsigned)f2bf(hi) << 16);
}

// ---------------- pass 1: per-block histogram of coarse bucket (512 thr) ----------------
__global__ __launch_bounds__(512) void hist_kernel(const int* __restrict__ col,
                                                   int* __restrict__ hist) {
    __shared__ int h[NBUCK];
    int tid = threadIdx.x;
    for (int i = tid; i < NBUCK; i += 512) h[i] = 0;
    __syncthreads();
    int base = blockIdx.x * SORT_ITEMS + tid * 4;
    #pragma unroll
    for (int l = 0; l < SORT_ITEMS / 2048; ++l) {
        int e = base + l * 2048;
        if (e < N_EDGES) {
            int4 c4 = *(const int4*)&col[e];
            atomicAdd(&h[c4.x >> 8], 1);
            atomicAdd(&h[c4.y >> 8], 1);
            atomicAdd(&h[c4.z >> 8], 1);
            atomicAdd(&h[c4.w >> 8], 1);
        }
    }
    __syncthreads();
    for (int i = tid; i < NBUCK; i += 512) hist[i * NB_SORT + blockIdx.x] = h[i];
}

// ---------------- scan of hist (block-local): 4096/block ----------------
__global__ __launch_bounds__(256) void scanA_kernel(int* __restrict__ a,
                                                    int* __restrict__ bsum, int n) {
    __shared__ int s[256];
    int tid = threadIdx.x;
    int base = blockIdx.x * 4096 + tid * 16;
    int v[16];
    int sum = 0;
    #pragma unroll
    for (int i = 0; i < 16; ++i) { v[i] = (base + i < n) ? a[base + i] : 0; sum += v[i]; }
    s[tid] = sum;
    __syncthreads();
    for (int d = 1; d < 256; d <<= 1) {
        int x = (tid >= d) ? s[tid - d] : 0;
        __syncthreads();
        s[tid] += x;
        __syncthreads();
    }
    int run = s[tid] - sum;
    #pragma unroll
    for (int i = 0; i < 16; ++i) {
        if (base + i < n) a[base + i] = run;
        run += v[i];
    }
    if (tid == 255) bsum[blockIdx.x] = s[255];
}

__global__ __launch_bounds__(256) void scanB_kernel(int* bsum, int nb) {
    __shared__ int s[256];
    int tid = threadIdx.x;
    int v = (tid < nb) ? bsum[tid] : 0;
    s[tid] = v;
    __syncthreads();
    for (int d = 1; d < 256; d <<= 1) {
        int x = (tid >= d) ? s[tid - d] : 0;
        __syncthreads();
        s[tid] += x;
        __syncthreads();
    }
    if (tid < nb) bsum[tid] = s[tid] - v;  // exclusive
}

// ---------------- pass 2: scatter edges into coarse-bucket regions (512 thr) ----------------
// rw2 entry: { row | (col&255)<<17 , ew }
__global__ __launch_bounds__(512) void scatter_sort_kernel(const int* __restrict__ col,
                                                           const int* __restrict__ row,
                                                           const float* __restrict__ ew,
                                                           const int* __restrict__ hist,
                                                           const int* __restrict__ bsum,
                                                           int2* __restrict__ rw2) {
    __shared__ int offs[NBUCK];
    int tid = threadIdx.x;
    for (int i = tid; i < NBUCK; i += 512) {
        int idx = i * NB_SORT + blockIdx.x;
        offs[i] = hist[idx] + bsum[idx >> 12];
    }
    __syncthreads();
    int base = blockIdx.x * SORT_ITEMS + tid * 4;
    #pragma unroll
    for (int l = 0; l < SORT_ITEMS / 2048; ++l) {
        int e = base + l * 2048;
        if (e < N_EDGES) {
            int4 c4 = *(const int4*)&col[e];
            int4 r4 = *(const int4*)&row[e];
            float4 w4 = *(const float4*)&ew[e];
            int p0 = atomicAdd(&offs[c4.x >> 8], 1);
            int p1 = atomicAdd(&offs[c4.y >> 8], 1);
            int p2 = atomicAdd(&offs[c4.z >> 8], 1);
            int p3 = atomicAdd(&offs[c4.w >> 8], 1);
            int2 v0; v0.x = r4.x | ((c4.x & 255) << 17); v0.y = __float_as_int(w4.x);
            int2 v1; v1.x = r4.y | ((c4.y & 255) << 17); v1.y = __float_as_int(w4.y);
            int2 v2; v2.x = r4.z | ((c4.z & 255) << 17); v2.y = __float_as_int(w4.z);
            int2 v3; v3.x = r4.w | ((c4.w & 255) << 17); v3.y = __float_as_int(w4.w);
            rw2[p0] = v0;
            rw2[p1] = v1;
            rw2[p2] = v2;
            rw2[p3] = v3;
        }
    }
}

// ---------------- pass 3: per-bucket CSR build + deg/dinv (512 thr) ----------------
__global__ __launch_bounds__(512) void build_kernel(const int* __restrict__ hist,
                                                    const int* __restrict__ bsum,
                                                    const int2* __restrict__ rw2,
                                                    int* __restrict__ off,
                                                    int* __restrict__ cnt,
                                                    float* __restrict__ dinv,
                                                    int2* __restrict__ csr) {
    int b = blockIdx.x;
    int tid = threadIdx.x;
    int ib = b * NB_SORT;
    int begin = hist[ib] + bsum[ib >> 12];
    int end = N_EDGES;
    if (b + 1 < NBUCK) {
        int ie = (b + 1) * NB_SORT;
        end = hist[ie] + bsum[ie >> 12];
    }
    __shared__ int lcnt[256];
    __shared__ float ldeg[256];
    __shared__ int s[512];
    __shared__ int curo[256];
    if (tid < 256) { lcnt[tid] = 0; ldeg[tid] = 0.f; }
    __syncthreads();
    for (int e = begin + tid; e < end; e += 2048) {
        int2 a0 = rw2[e];
        int e1 = e + 512, e2 = e + 1024, e3 = e + 1536;
        int2 a1 = (e1 < end) ? rw2[e1] : make_int2(0, 0);
        int2 a2 = (e2 < end) ? rw2[e2] : make_int2(0, 0);
        int2 a3 = (e3 < end) ? rw2[e3] : make_int2(0, 0);
        atomicAdd(&lcnt[a0.x >> 17], 1);
        atomicAdd(&ldeg[a0.x >> 17], __int_as_float(a0.y));
        if (e1 < end) { atomicAdd(&lcnt[a1.x >> 17], 1); atomicAdd(&ldeg[a1.x >> 17], __int_as_float(a1.y)); }
        if (e2 < end) { atomicAdd(&lcnt[a2.x >> 17], 1); atomicAdd(&ldeg[a2.x >> 17], __int_as_float(a2.y)); }
        if (e3 < end) { atomicAdd(&lcnt[a3.x >> 17], 1); atomicAdd(&ldeg[a3.x >> 17], __int_as_float(a3.y)); }
    }
    __syncthreads();
    int v = (tid < 256) ? lcnt[tid] : 0;
    s[tid] = v;
    __syncthreads();
    for (int d = 1; d < 512; d <<= 1) {
        int x = (tid >= d) ? s[tid - d] : 0;
        __syncthreads();
        s[tid] += x;
        __syncthreads();
    }
    if (tid < 256) {
        int excl = s[tid] - v;
        int node = (b << 8) + tid;
        if (node < N_NODES) {
            off[node] = begin + excl;
            cnt[node] = v;
            dinv[node] = rsqrtf(1.0f + ldeg[tid]);
        }
        curo[tid] = begin + excl;
    }
    __syncthreads();
    for (int e = begin + tid; e < end; e += 2048) {
        int2 a0 = rw2[e];
        int e1 = e + 512, e2 = e + 1024, e3 = e + 1536;
        int2 a1 = (e1 < end) ? rw2[e1] : make_int2(0, 0);
        int2 a2 = (e2 < end) ? rw2[e2] : make_int2(0, 0);
        int2 a3 = (e3 < end) ? rw2[e3] : make_int2(0, 0);
        int p0 = atomicAdd(&curo[a0.x >> 17], 1);
        csr[p0] = make_int2(a0.x & ROW_MASK, a0.y);
        if (e1 < end) { int p = atomicAdd(&curo[a1.x >> 17], 1); csr[p] = make_int2(a1.x & ROW_MASK, a1.y); }
        if (e2 < end) { int p = atomicAdd(&curo[a2.x >> 17], 1); csr[p] = make_int2(a2.x & ROW_MASK, a2.y); }
        if (e3 < end) { int p = atomicAdd(&curo[a3.x >> 17], 1); csr[p] = make_int2(a3.x & ROW_MASK, a3.y); }
    }
}

// ------- tiled f32-input GEMM, bf16 output: H = bf16((X@W)*scale) -------
template <int IN, int OUT, int ROWS>
__global__ __launch_bounds__(256) void gemm_bf16_kernel(const float* __restrict__ X,
                                                        const float* __restrict__ W,
                                                        const float* __restrict__ scale,
                                                        unsigned short* __restrict__ H, int n) {
    constexpr int BK = 16;
    constexpr int TX = OUT / 4;
    constexpr int TY = ROWS / 8;
    static_assert(TX * TY == 256, "block must be 256 threads");
    __shared__ float xsT[BK][ROWS + 4];
    __shared__ float ws[BK][OUT + 4];
    int tid = threadIdx.x;
    int tx = tid % TX, ty = tid / TX;
    int r0 = blockIdx.x * ROWS;
    float acc[8][4] = {};
    for (int k0 = 0; k0 < IN; k0 += BK) {
        constexpr int XL = (ROWS * BK) / (256 * 4);
        #pragma unroll
        for (int l = 0; l < XL; ++l) {
            int t = tid + l * 256;
            int rr = t >> 2;
            int kp = (t & 3) * 4;
            float4 v = make_float4(0.f, 0.f, 0.f, 0.f);
            int gr = r0 + rr;
            if (gr < n) v = *(const float4*)&X[(size_t)gr * IN + k0 + kp];
            xsT[kp + 0][rr] = v.x;
            xsT[kp + 1][rr] = v.y;
            xsT[kp + 2][rr] = v.z;
            xsT[kp + 3][rr] = v.w;
        }
        constexpr int WL = (BK * OUT) / 4;
        if (WL == 256 || tid < WL) {
            int kr = tid / TX;
            int cp = (tid % TX) * 4;
            float4 v = *(const float4*)&W[(size_t)(k0 + kr) * OUT + cp];
            *(float4*)&ws[kr][cp] = v;
        }
        __syncthreads();
        #pragma unroll
        for (int kk = 0; kk < BK; ++kk) {
            float4 a0 = *(const float4*)&xsT[kk][ty * 8];
            float4 a1 = *(const float4*)&xsT[kk][ty * 8 + 4];
            float4 b = *(const float4*)&ws[kk][tx * 4];
            float av[8] = {a0.x, a0.y, a0.z, a0.w, a1.x, a1.y, a1.z, a1.w};
            float bv[4] = {b.x, b.y, b.z, b.w};
            #pragma unroll
            for (int i = 0; i < 8; ++i) {
                #pragma unroll
                for (int j = 0; j < 4; ++j) acc[i][j] = fmaf(av[i], bv[j], acc[i][j]);
            }
        }
        __syncthreads();
    }
    #pragma unroll
    for (int i = 0; i < 8; ++i) {
        int gr = r0 + ty * 8 + i;
        if (gr < n) {
            float sc = scale[gr];
            ushort4 o;
            o.x = f2bf(acc[i][0] * sc);
            o.y = f2bf(acc[i][1] * sc);
            o.z = f2bf(acc[i][2] * sc);
            o.w = f2bf(acc[i][3] * sc);
            *(ushort4*)&H[(size_t)gr * OUT + tx * 4] = o;
        }
    }
}

// ---------------- fused agg1 + gemm2: wave per node, W2 in LDS ----------------
// Phase A: identical loop to the 57us agg1 (no extra registers live).
// Phase B: per-node, read W2 from LDS (padded rows, 2-way max conflict),
// matvec + fb-reduce + dinv scale, write h2t bf16.
__global__ __launch_bounds__(256) void agg1_kernel(const int2* __restrict__ csr,
                                                   const int* __restrict__ off,
                                                   const int* __restrict__ cnt,
                                                   const float* __restrict__ dinv,
                                                   const unsigned short* __restrict__ h1t,
                                                   const float* __restrict__ b1,
                                                   const float* __restrict__ W2g,
                                                   unsigned short* __restrict__ h2t) {
    __shared__ float w2s[64][33];
    int tid = threadIdx.x;
    {   // stage W2 (64x32) once per block: thread t covers 8 consecutive elems
        int idx = tid * 8;
        int r = idx >> 5, c0 = idx & 31;
        float4 a = *(const float4*)&W2g[idx];
        float4 b = *(const float4*)&W2g[idx + 4];
        w2s[r][c0 + 0] = a.x; w2s[r][c0 + 1] = a.y; w2s[r][c0 + 2] = a.z; w2s[r][c0 + 3] = a.w;
        w2s[r][c0 + 4] = b.x; w2s[r][c0 + 5] = b.y; w2s[r][c0 + 6] = b.z; w2s[r][c0 + 7] = b.w;
    }
    __syncthreads();
    int lane = tid & 63;
    int node = blockIdx.x * 4 + (tid >> 6);
    int es = lane >> 3;   // edge slot 0..7
    int fb = lane & 7;    // feat block 0..7 (8 feats each)
    int s = off[node], c = cnt[node];
    float acc[8] = {};
    for (int j0 = 0; j0 < c; j0 += 64) {
        int m = min(64, c - j0);
        int2 e = make_int2(0, 0);
        if (lane < m) e = csr[s + j0 + lane];
        int ng = (m + 7) >> 3;
        int g = 0;
        for (; g + 2 <= ng; g += 2) {
            int s0 = g * 8 + es;
            int s1 = s0 + 8;
            int r0 = __shfl(e.x, s0);
            float w0 = __int_as_float(__shfl(e.y, s0));
            int r1 = __shfl(e.x, s1);
            float w1 = __int_as_float(__shfl(e.y, s1));
            int4 d0 = *(const int4*)(h1t + (((size_t)r0) << 6) + (fb << 3));
            int4 d1 = *(const int4*)(h1t + (((size_t)r1) << 6) + (fb << 3));
            acc[0] = fmaf(w0, bfl(d0.x), acc[0]);
            acc[1] = fmaf(w0, bfh(d0.x), acc[1]);
            acc[2] = fmaf(w0, bfl(d0.y), acc[2]);
            acc[3] = fmaf(w0, bfh(d0.y), acc[3]);
            acc[4] = fmaf(w0, bfl(d0.z), acc[4]);
            acc[5] = fmaf(w0, bfh(d0.z), acc[5]);
            acc[6] = fmaf(w0, bfl(d0.w), acc[6]);
            acc[7] = fmaf(w0, bfh(d0.w), acc[7]);
            acc[0] = fmaf(w1, bfl(d1.x), acc[0]);
            acc[1] = fmaf(w1, bfh(d1.x), acc[1]);
            acc[2] = fmaf(w1, bfl(d1.y), acc[2]);
            acc[3] = fmaf(w1, bfh(d1.y), acc[3]);
            acc[4] = fmaf(w1, bfl(d1.z), acc[4]);
            acc[5] = fmaf(w1, bfh(d1.z), acc[5]);
            acc[6] = fmaf(w1, bfl(d1.w), acc[6]);
            acc[7] = fmaf(w1, bfh(d1.w), acc[7]);
        }
        if (g < ng) {
            int s0 = g * 8 + es;
            int r0 = __shfl(e.x, s0);
            float w0 = __int_as_float(__shfl(e.y, s0));
            int4 d0 = *(const int4*)(h1t + (((size_t)r0) << 6) + (fb << 3));
            acc[0] = fmaf(w0, bfl(d0.x), acc[0]);
            acc[1] = fmaf(w0, bfh(d0.x), acc[1]);
            acc[2] = fmaf(w0, bfl(d0.y), acc[2]);
            acc[3] = fmaf(w0, bfh(d0.y), acc[3]);
            acc[4] = fmaf(w0, bfl(d0.z), acc[4]);
            acc[5] = fmaf(w0, bfh(d0.z), acc[5]);
            acc[6] = fmaf(w0, bfl(d0.w), acc[6]);
            acc[7] = fmaf(w0, bfh(d0.w), acc[7]);
        }
    }
    #pragma unroll
    for (int mask = 8; mask <= 32; mask <<= 1) {
        #pragma unroll
        for (int k = 0; k < 8; ++k) acc[k] += __shfl_xor(acc[k], mask);
    }
    // all lanes: finish h1p feats fb*8..fb*8+7 (agg + self + dinv + bias + ReLU)
    float di = dinv[node];
    int4 ds = *(const int4*)(h1t + (((size_t)node) << 6) + (fb << 3));
    float4 bv0 = *(const float4*)&b1[fb * 8];
    float4 bv1 = *(const float4*)&b1[fb * 8 + 4];
    float hp[8];
    hp[0] = fmaxf(fmaf(acc[0] + bfl(ds.x), di, bv0.x), 0.f);
    hp[1] = fmaxf(fmaf(acc[1] + bfh(ds.x), di, bv0.y), 0.f);
    hp[2] = fmaxf(fmaf(acc[2] + bfl(ds.y), di, bv0.z), 0.f);
    hp[3] = fmaxf(fmaf(acc[3] + bfh(ds.y), di, bv0.w), 0.f);
    hp[4] = fmaxf(fmaf(acc[4] + bfl(ds.z), di, bv1.x), 0.f);
    hp[5] = fmaxf(fmaf(acc[5] + bfh(ds.z), di, bv1.y), 0.f);
    hp[6] = fmaxf(fmaf(acc[6] + bfl(ds.w), di, bv1.z), 0.f);
    hp[7] = fmaxf(fmaf(acc[7] + bfh(ds.w), di, bv1.w), 0.f);
    // matvec partials for out-cols es*4..es*4+3 (W2 from LDS)
    float p0 = 0.f, p1 = 0.f, p2 = 0.f, p3 = 0.f;
    #pragma unroll
    for (int i = 0; i < 8; ++i) {
        const float* wr = &w2s[fb * 8 + i][es * 4];
        p0 = fmaf(hp[i], wr[0], p0);
        p1 = fmaf(hp[i], wr[1], p1);
        p2 = fmaf(hp[i], wr[2], p2);
        p3 = fmaf(hp[i], wr[3], p3);
    }
    // reduce over fb (lane bits 0..2)
    #pragma unroll
    for (int mask = 1; mask <= 4; mask <<= 1) {
        p0 += __shfl_xor(p0, mask);
        p1 += __shfl_xor(p1, mask);
        p2 += __shfl_xor(p2, mask);
        p3 += __shfl_xor(p3, mask);
    }
    if (fb == 0) {  // 8 lanes, es = 0..7 -> cols es*4..es*4+3
        unsigned lo = pack2bf(p0 * di, p1 * di);
        unsigned hi = pack2bf(p2 * di, p3 * di);
        *(int2*)(h2t + (((size_t)node) << 5) + (es << 2)) = make_int2((int)lo, (int)hi);
    }
}

// ---------------- aggregation conv2: 32 feats, half-wave per node ----------------
__global__ __launch_bounds__(256) void agg2_kernel(const int2* __restrict__ csr,
                                                   const int* __restrict__ off,
                                                   const int* __restrict__ cnt,
                                                   const float* __restrict__ dinv,
                                                   const unsigned short* __restrict__ h2t,
                                                   const float* __restrict__ b2,
                                                   float* __restrict__ h2p) {
    int lane = threadIdx.x & 63;
    int half = lane >> 5;
    int hl = lane & 31;
    int es = hl >> 2;   // edge slot 0..7
    int fb = hl & 3;    // feat block 0..3 (8 feats each)
    int wid = threadIdx.x >> 6;
    int node = blockIdx.x * 8 + wid * 2 + half;
    int s = off[node], c = cnt[node];
    int lbase = half << 5;
    float acc[8] = {};
    for (int j0 = 0; j0 < c; j0 += 32) {
        int m = min(32, c - j0);
        int2 e = make_int2(0, 0);
        if (hl < m) e = csr[s + j0 + hl];
        int ng = (m + 7) >> 3;
        int g = 0;
        for (; g + 2 <= ng; g += 2) {
            int s0 = lbase + g * 8 + es;
            int s1 = s0 + 8;
            int r0 = __shfl(e.x, s0);
            float w0 = __int_as_float(__shfl(e.y, s0));
            int r1 = __shfl(e.x, s1);
            float w1 = __int_as_float(__shfl(e.y, s1));
            int4 d0 = *(const int4*)(h2t + (((size_t)r0) << 5) + (fb << 3));
            int4 d1 = *(const int4*)(h2t + (((size_t)r1) << 5) + (fb << 3));
            acc[0] = fmaf(w0, bfl(d0.x), acc[0]);
            acc[1] = fmaf(w0, bfh(d0.x), acc[1]);
            acc[2] = fmaf(w0, bfl(d0.y), acc[2]);
            acc[3] = fmaf(w0, bfh(d0.y), acc[3]);
            acc[4] = fmaf(w0, bfl(d0.z), acc[4]);
            acc[5] = fmaf(w0, bfh(d0.z), acc[5]);
            acc[6] = fmaf(w0, bfl(d0.w), acc[6]);
            acc[7] = fmaf(w0, bfh(d0.w), acc[7]);
            acc[0] = fmaf(w1, bfl(d1.x), acc[0]);
            acc[1] = fmaf(w1, bfh(d1.x), acc[1]);
            acc[2] = fmaf(w1, bfl(d1.y), acc[2]);
            acc[3] = fmaf(w1, bfh(d1.y), acc[3]);
            acc[4] = fmaf(w1, bfl(d1.z), acc[4]);
            acc[5] = fmaf(w1, bfh(d1.z), acc[5]);
            acc[6] = fmaf(w1, bfl(d1.w), acc[6]);
            acc[7] = fmaf(w1, bfh(d1.w), acc[7]);
        }
        if (g < ng) {
            int s0 = lbase + g * 8 + es;
            int r0 = __shfl(e.x, s0);
            float w0 = __int_as_float(__shfl(e.y, s0));
            int4 d0 = *(const int4*)(h2t + (((size_t)r0) << 5) + (fb << 3));
            acc[0] = fmaf(w0, bfl(d0.x), acc[0]);
            acc[1] = fmaf(w0, bfh(d0.x), acc[1]);
            acc[2] = fmaf(w0, bfl(d0.y), acc[2]);
            acc[3] = fmaf(w0, bfh(d0.y), acc[3]);
            acc[4] = fmaf(w0, bfl(d0.z), acc[4]);
            acc[5] = fmaf(w0, bfh(d0.z), acc[5]);
            acc[6] = fmaf(w0, bfl(d0.w), acc[6]);
            acc[7] = fmaf(w0, bfh(d0.w), acc[7]);
        }
    }
    #pragma unroll
    for (int mask = 4; mask <= 16; mask <<= 1) {
        #pragma unroll
        for (int k = 0; k < 8; ++k) acc[k] += __shfl_xor(acc[k], mask);
    }
    if (es == 0) {  // hl 0..3; fb == hl
        float di = dinv[node];
        int4 ds = *(const int4*)(h2t + (((size_t)node) << 5) + (fb << 3));
        float4 bv0 = *(const float4*)&b2[fb * 8];
        float4 bv1 = *(const float4*)&b2[fb * 8 + 4];
        float4 o0, o1;
        o0.x = fmaf(acc[0] + bfl(ds.x), di, bv0.x);
        o0.y = fmaf(acc[1] + bfh(ds.x), di, bv0.y);
        o0.z = fmaf(acc[2] + bfl(ds.y), di, bv0.z);
        o0.w = fmaf(acc[3] + bfh(ds.y), di, bv0.w);
        o1.x = fmaf(acc[4] + bfl(ds.z), di, bv1.x);
        o1.y = fmaf(acc[5] + bfh(ds.z), di, bv1.y);
        o1.z = fmaf(acc[6] + bfl(ds.w), di, bv1.z);
        o1.w = fmaf(acc[7] + bfh(ds.w), di, bv1.w);
        float* po = h2p + (size_t)node * 32 + fb * 8;
        *(float4*)po = o0;
        *(float4*)(po + 4) = o1;
    }
}

// ---------------- fused pool + MLP head: one block per graph ----------------
__global__ __launch_bounds__(256) void pool_head_kernel(const float* __restrict__ h2p,
                                                        const int* __restrict__ batch,
                                                        const float* __restrict__ Wl1,
                                                        const float* __restrict__ bl1,
                                                        const float* __restrict__ Wl2,
                                                        const float* __restrict__ bl2,
                                                        float* __restrict__ out) {
    int g = blockIdx.x;
    int lo = 0, hi = N_NODES;
    while (lo < hi) { int m = (lo + hi) >> 1; if (batch[m] < g) lo = m + 1; else hi = m; }
    int start = lo;
    hi = N_NODES;
    while (lo < hi) { int m = (lo + hi) >> 1; if (batch[m] < g + 1) lo = m + 1; else hi = m; }
    int end = lo;
    int f = threadIdx.x & 31, grp = threadIdx.x >> 5;
    float acc = 0.f;
    for (int n = start + grp; n < end; n += 8) acc += h2p[(size_t)n * 32 + f];
    __shared__ float red[8][32];
    __shared__ float usum[32];
    red[grp][f] = acc;
    __syncthreads();
    if (threadIdx.x < 32) {
        float sum = 0.f;
        #pragma unroll
        for (int k = 0; k < 8; ++k) sum += red[k][threadIdx.x];
        usum[threadIdx.x] = sum;
    }
    __syncthreads();
    if (threadIdx.x < 16) {
        int j = threadIdx.x;
        float h = bl1[j];
        #pragma unroll
        for (int k = 0; k < 32; ++k) h = fmaf(usum[k], Wl1[k * 16 + j], h);
        float t = fmaxf(h, 0.f) * Wl2[j];
        t += __shfl_xor(t, 1);
        t += __shfl_xor(t, 2);
        t += __shfl_xor(t, 4);
        t += __shfl_xor(t, 8);
        if (j == 0) out[g] = t + bl2[0];
    }
}

extern "C" void kernel_launch(void* const* d_in, const int* in_sizes, int n_in,
                              void* d_out, int out_size, void* d_ws, size_t ws_size,
                              hipStream_t stream) {
    const float* x     = (const float*)d_in[0];
    const int*   ei    = (const int*)d_in[1];
    const float* ew    = (const float*)d_in[2];
    const int*   batch = (const int*)d_in[3];
    const float* W1    = (const float*)d_in[4];
    const float* b1    = (const float*)d_in[5];
    const float* W2    = (const float*)d_in[6];
    const float* b2    = (const float*)d_in[7];
    const float* Wl1   = (const float*)d_in[8];
    const float* bl1   = (const float*)d_in[9];
    const float* Wl2   = (const float*)d_in[10];
    const float* bl2   = (const float*)d_in[11];
    float* out = (float*)d_out;

    const int* row = ei;
    const int* col = ei + N_EDGES;

    char* p = (char*)d_ws;
    auto alloc = [&](size_t bytes) {
        char* q = p;
        p += (bytes + 255) & ~(size_t)255;
        return q;
    };
    int*   hist   = (int*)alloc((size_t)HIST_N * 4);
    int*   bsum   = (int*)alloc(1024 * 4);
    int2*  rw2    = (int2*)alloc((size_t)N_EDGES * 8);
    int*   off    = (int*)alloc(N_NODES * 4);
    int*   cnt    = (int*)alloc(N_NODES * 4);
    float* dinv   = (float*)alloc(N_NODES * 4);
    int2*  csr    = (int2*)alloc((size_t)N_EDGES * 8);
    unsigned short* h1t = (unsigned short*)rw2;  // alias: rw2 dead after build
    unsigned short* h2t = (unsigned short*)alloc((size_t)N_NODES * 32 * 2);
    float* h2p    = (float*)alloc((size_t)N_NODES * 32 * 4);

    const int nbScan = (HIST_N + 4095) / 4096;  // 38

    hist_kernel<<<NB_SORT, 512, 0, stream>>>(col, hist);
    scanA_kernel<<<nbScan, 256, 0, stream>>>(hist, bsum, HIST_N);
    scanB_kernel<<<1, 256, 0, stream>>>(bsum, nbScan);
    scatter_sort_kernel<<<NB_SORT, 512, 0, stream>>>(col, row, ew, hist, bsum, rw2);
    build_kernel<<<NBUCK, 512, 0, stream>>>(hist, bsum, rw2, off, cnt, dinv, csr);

    gemm_bf16_kernel<128, 64, 128><<<(N_NODES + 127) / 128, 256, 0, stream>>>(x, W1, dinv, h1t, N_NODES);
    agg1_kernel<<<N_NODES / 4, 256, 0, stream>>>(csr, off, cnt, dinv, h1t, b1, W2, h2t);
    agg2_kernel<<<N_NODES / 8, 256, 0, stream>>>(csr, off, cnt, dinv, h2t, b2, h2p);
    pool_head_kernel<<<N_GRAPHS, 256, 0, stream>>>(h2p, batch, Wl1, bl1, Wl2, bl2, out);
}

// Round 14
// 241.323 us; speedup vs baseline: 1.2459x; 1.0732x over previous
//
#include <hip/hip_runtime.h>
#include <hip/hip_bf16.h>

#define N_NODES 100000
#define N_EDGES 3200000
#define N_GRAPHS 256

#define NBUCK 391                 // ceil(N_NODES / 256) coarse buckets (col >> 8)
#define SORT_ITEMS 8192           // edges per block in hist/scatter passes
#define NB_SORT ((N_EDGES + SORT_ITEMS - 1) / SORT_ITEMS)   // 391
#define HIST_N (NBUCK * NB_SORT)  // 152,881
#define ROW_MASK 131071           // 2^17 - 1 (N_NODES < 2^17)

__device__ __forceinline__ float bfl(int d) {  // low bf16 of dword -> f32
    return __uint_as_float(((unsigned)d) << 16);
}
__device__ __forceinline__ float bfh(int d) {  // high bf16 of dword -> f32
    return __uint_as_float(((unsigned)d) & 0xffff0000u);
}
__device__ __forceinline__ unsigned short f2bf(float f) {
    __hip_bfloat16 b = __float2bfloat16(f);
    return *(unsigned short*)&b;
}
__device__ __forceinline__ unsigned pack2bf(float lo, float hi) {
    return (unsigned)f2bf(lo) | ((unsigned)f2bf(hi) << 16);
}

// ---------------- pass 1: per-block histogram of coarse bucket (512 thr) ----------------
__global__ __launch_bounds__(512) void hist_kernel(const int* __restrict__ col,
                                                   int* __restrict__ hist) {
    __shared__ int h[NBUCK];
    int tid = threadIdx.x;
    for (int i = tid; i < NBUCK; i += 512) h[i] = 0;
    __syncthreads();
    int base = blockIdx.x * SORT_ITEMS + tid * 4;
    #pragma unroll
    for (int l = 0; l < SORT_ITEMS / 2048; ++l) {
        int e = base + l * 2048;
        if (e < N_EDGES) {
            int4 c4 = *(const int4*)&col[e];
            atomicAdd(&h[c4.x >> 8], 1);
            atomicAdd(&h[c4.y >> 8], 1);
            atomicAdd(&h[c4.z >> 8], 1);
            atomicAdd(&h[c4.w >> 8], 1);
        }
    }
    __syncthreads();
    for (int i = tid; i < NBUCK; i += 512) hist[i * NB_SORT + blockIdx.x] = h[i];
}

// ---------------- scan of hist (block-local): 4096/block ----------------
__global__ __launch_bounds__(256) void scanA_kernel(int* __restrict__ a,
                                                    int* __restrict__ bsum, int n) {
    __shared__ int s[256];
    int tid = threadIdx.x;
    int base = blockIdx.x * 4096 + tid * 16;
    int v[16];
    int sum = 0;
    #pragma unroll
    for (int i = 0; i < 16; ++i) { v[i] = (base + i < n) ? a[base + i] : 0; sum += v[i]; }
    s[tid] = sum;
    __syncthreads();
    for (int d = 1; d < 256; d <<= 1) {
        int x = (tid >= d) ? s[tid - d] : 0;
        __syncthreads();
        s[tid] += x;
        __syncthreads();
    }
    int run = s[tid] - sum;
    #pragma unroll
    for (int i = 0; i < 16; ++i) {
        if (base + i < n) a[base + i] = run;
        run += v[i];
    }
    if (tid == 255) bsum[blockIdx.x] = s[255];
}

__global__ __launch_bounds__(256) void scanB_kernel(int* bsum, int nb) {
    __shared__ int s[256];
    int tid = threadIdx.x;
    int v = (tid < nb) ? bsum[tid] : 0;
    s[tid] = v;
    __syncthreads();
    for (int d = 1; d < 256; d <<= 1) {
        int x = (tid >= d) ? s[tid - d] : 0;
        __syncthreads();
        s[tid] += x;
        __syncthreads();
    }
    if (tid < nb) bsum[tid] = s[tid] - v;  // exclusive
}

// ---------------- pass 2: scatter edges into coarse-bucket regions (512 thr) ----------------
// rw2 entry: { row | (col&255)<<17 , ew }
__global__ __launch_bounds__(512) void scatter_sort_kernel(const int* __restrict__ col,
                                                           const int* __restrict__ row,
                                                           const float* __restrict__ ew,
                                                           const int* __restrict__ hist,
                                                           const int* __restrict__ bsum,
                                                           int2* __restrict__ rw2) {
    __shared__ int offs[NBUCK];
    int tid = threadIdx.x;
    for (int i = tid; i < NBUCK; i += 512) {
        int idx = i * NB_SORT + blockIdx.x;
        offs[i] = hist[idx] + bsum[idx >> 12];
    }
    __syncthreads();
    int base = blockIdx.x * SORT_ITEMS + tid * 4;
    #pragma unroll
    for (int l = 0; l < SORT_ITEMS / 2048; ++l) {
        int e = base + l * 2048;
        if (e < N_EDGES) {
            int4 c4 = *(const int4*)&col[e];
            int4 r4 = *(const int4*)&row[e];
            float4 w4 = *(const float4*)&ew[e];
            int p0 = atomicAdd(&offs[c4.x >> 8], 1);
            int p1 = atomicAdd(&offs[c4.y >> 8], 1);
            int p2 = atomicAdd(&offs[c4.z >> 8], 1);
            int p3 = atomicAdd(&offs[c4.w >> 8], 1);
            int2 v0; v0.x = r4.x | ((c4.x & 255) << 17); v0.y = __float_as_int(w4.x);
            int2 v1; v1.x = r4.y | ((c4.y & 255) << 17); v1.y = __float_as_int(w4.y);
            int2 v2; v2.x = r4.z | ((c4.z & 255) << 17); v2.y = __float_as_int(w4.z);
            int2 v3; v3.x = r4.w | ((c4.w & 255) << 17); v3.y = __float_as_int(w4.w);
            rw2[p0] = v0;
            rw2[p1] = v1;
            rw2[p2] = v2;
            rw2[p3] = v3;
        }
    }
}

// ---------------- pass 3: per-bucket CSR build + deg/dinv (512 thr) ----------------
__global__ __launch_bounds__(512) void build_kernel(const int* __restrict__ hist,
                                                    const int* __restrict__ bsum,
                                                    const int2* __restrict__ rw2,
                                                    int* __restrict__ off,
                                                    int* __restrict__ cnt,
                                                    float* __restrict__ dinv,
                                                    int2* __restrict__ csr) {
    int b = blockIdx.x;
    int tid = threadIdx.x;
    int ib = b * NB_SORT;
    int begin = hist[ib] + bsum[ib >> 12];
    int end = N_EDGES;
    if (b + 1 < NBUCK) {
        int ie = (b + 1) * NB_SORT;
        end = hist[ie] + bsum[ie >> 12];
    }
    __shared__ int lcnt[256];
    __shared__ float ldeg[256];
    __shared__ int s[512];
    __shared__ int curo[256];
    if (tid < 256) { lcnt[tid] = 0; ldeg[tid] = 0.f; }
    __syncthreads();
    for (int e = begin + tid; e < end; e += 2048) {
        int2 a0 = rw2[e];
        int e1 = e + 512, e2 = e + 1024, e3 = e + 1536;
        int2 a1 = (e1 < end) ? rw2[e1] : make_int2(0, 0);
        int2 a2 = (e2 < end) ? rw2[e2] : make_int2(0, 0);
        int2 a3 = (e3 < end) ? rw2[e3] : make_int2(0, 0);
        atomicAdd(&lcnt[a0.x >> 17], 1);
        atomicAdd(&ldeg[a0.x >> 17], __int_as_float(a0.y));
        if (e1 < end) { atomicAdd(&lcnt[a1.x >> 17], 1); atomicAdd(&ldeg[a1.x >> 17], __int_as_float(a1.y)); }
        if (e2 < end) { atomicAdd(&lcnt[a2.x >> 17], 1); atomicAdd(&ldeg[a2.x >> 17], __int_as_float(a2.y)); }
        if (e3 < end) { atomicAdd(&lcnt[a3.x >> 17], 1); atomicAdd(&ldeg[a3.x >> 17], __int_as_float(a3.y)); }
    }
    __syncthreads();
    int v = (tid < 256) ? lcnt[tid] : 0;
    s[tid] = v;
    __syncthreads();
    for (int d = 1; d < 512; d <<= 1) {
        int x = (tid >= d) ? s[tid - d] : 0;
        __syncthreads();
        s[tid] += x;
        __syncthreads();
    }
    if (tid < 256) {
        int excl = s[tid] - v;
        int node = (b << 8) + tid;
        if (node < N_NODES) {
            off[node] = begin + excl;
            cnt[node] = v;
            dinv[node] = rsqrtf(1.0f + ldeg[tid]);
        }
        curo[tid] = begin + excl;
    }
    __syncthreads();
    for (int e = begin + tid; e < end; e += 2048) {
        int2 a0 = rw2[e];
        int e1 = e + 512, e2 = e + 1024, e3 = e + 1536;
        int2 a1 = (e1 < end) ? rw2[e1] : make_int2(0, 0);
        int2 a2 = (e2 < end) ? rw2[e2] : make_int2(0, 0);
        int2 a3 = (e3 < end) ? rw2[e3] : make_int2(0, 0);
        int p0 = atomicAdd(&curo[a0.x >> 17], 1);
        csr[p0] = make_int2(a0.x & ROW_MASK, a0.y);
        if (e1 < end) { int p = atomicAdd(&curo[a1.x >> 17], 1); csr[p] = make_int2(a1.x & ROW_MASK, a1.y); }
        if (e2 < end) { int p = atomicAdd(&curo[a2.x >> 17], 1); csr[p] = make_int2(a2.x & ROW_MASK, a2.y); }
        if (e3 < end) { int p = atomicAdd(&curo[a3.x >> 17], 1); csr[p] = make_int2(a3.x & ROW_MASK, a3.y); }
    }
}

// ------- tiled f32-input GEMM, bf16 output: H = bf16((X@W)*scale) -------
template <int IN, int OUT, int ROWS>
__global__ __launch_bounds__(256) void gemm_bf16_kernel(const float* __restrict__ X,
                                                        const float* __restrict__ W,
                                                        const float* __restrict__ scale,
                                                        unsigned short* __restrict__ H, int n) {
    constexpr int BK = 16;
    constexpr int TX = OUT / 4;
    constexpr int TY = ROWS / 8;
    static_assert(TX * TY == 256, "block must be 256 threads");
    __shared__ float xsT[BK][ROWS + 4];
    __shared__ float ws[BK][OUT + 4];
    int tid = threadIdx.x;
    int tx = tid % TX, ty = tid / TX;
    int r0 = blockIdx.x * ROWS;
    float acc[8][4] = {};
    for (int k0 = 0; k0 < IN; k0 += BK) {
        constexpr int XL = (ROWS * BK) / (256 * 4);
        #pragma unroll
        for (int l = 0; l < XL; ++l) {
            int t = tid + l * 256;
            int rr = t >> 2;
            int kp = (t & 3) * 4;
            float4 v = make_float4(0.f, 0.f, 0.f, 0.f);
            int gr = r0 + rr;
            if (gr < n) v = *(const float4*)&X[(size_t)gr * IN + k0 + kp];
            xsT[kp + 0][rr] = v.x;
            xsT[kp + 1][rr] = v.y;
            xsT[kp + 2][rr] = v.z;
            xsT[kp + 3][rr] = v.w;
        }
        constexpr int WL = (BK * OUT) / 4;
        if (WL == 256 || tid < WL) {
            int kr = tid / TX;
            int cp = (tid % TX) * 4;
            float4 v = *(const float4*)&W[(size_t)(k0 + kr) * OUT + cp];
            *(float4*)&ws[kr][cp] = v;
        }
        __syncthreads();
        #pragma unroll
        for (int kk = 0; kk < BK; ++kk) {
            float4 a0 = *(const float4*)&xsT[kk][ty * 8];
            float4 a1 = *(const float4*)&xsT[kk][ty * 8 + 4];
            float4 b = *(const float4*)&ws[kk][tx * 4];
            float av[8] = {a0.x, a0.y, a0.z, a0.w, a1.x, a1.y, a1.z, a1.w};
            float bv[4] = {b.x, b.y, b.z, b.w};
            #pragma unroll
            for (int i = 0; i < 8; ++i) {
                #pragma unroll
                for (int j = 0; j < 4; ++j) acc[i][j] = fmaf(av[i], bv[j], acc[i][j]);
            }
        }
        __syncthreads();
    }
    #pragma unroll
    for (int i = 0; i < 8; ++i) {
        int gr = r0 + ty * 8 + i;
        if (gr < n) {
            float sc = scale[gr];
            ushort4 o;
            o.x = f2bf(acc[i][0] * sc);
            o.y = f2bf(acc[i][1] * sc);
            o.z = f2bf(acc[i][2] * sc);
            o.w = f2bf(acc[i][3] * sc);
            *(ushort4*)&H[(size_t)gr * OUT + tx * 4] = o;
        }
    }
}

// ------- tiled bf16-input GEMM, bf16 output: H = bf16((X@W)*scale) -------
template <int IN, int OUT, int ROWS>
__global__ __launch_bounds__(256) void gemm_bf16in_kernel(const unsigned short* __restrict__ X,
                                                          const float* __restrict__ W,
                                                          const float* __restrict__ scale,
                                                          unsigned short* __restrict__ H, int n) {
    constexpr int BK = 16;
    constexpr int TX = OUT / 4;
    constexpr int TY = ROWS / 8;
    static_assert(TX * TY == 256, "block must be 256 threads");
    __shared__ float xsT[BK][ROWS + 4];
    __shared__ float ws[BK][OUT + 4];
    int tid = threadIdx.x;
    int tx = tid % TX, ty = tid / TX;
    int r0 = blockIdx.x * ROWS;
    float acc[8][4] = {};
    for (int k0 = 0; k0 < IN; k0 += BK) {
        constexpr int XL = (ROWS * BK) / (256 * 4);
        #pragma unroll
        for (int l = 0; l < XL; ++l) {
            int t = tid + l * 256;
            int rr = t >> 2;
            int kp = (t & 3) * 4;
            int gr = r0 + rr;
            float f0 = 0.f, f1 = 0.f, f2 = 0.f, f3 = 0.f;
            if (gr < n) {
                ushort4 v = *(const ushort4*)&X[(size_t)gr * IN + k0 + kp];
                f0 = bfl(v.x); f1 = bfl(v.y); f2 = bfl(v.z); f3 = bfl(v.w);
            }
            xsT[kp + 0][rr] = f0;
            xsT[kp + 1][rr] = f1;
            xsT[kp + 2][rr] = f2;
            xsT[kp + 3][rr] = f3;
        }
        constexpr int WL = (BK * OUT) / 4;
        if (WL == 256 || tid < WL) {
            int kr = tid / TX;
            int cp = (tid % TX) * 4;
            float4 v = *(const float4*)&W[(size_t)(k0 + kr) * OUT + cp];
            *(float4*)&ws[kr][cp] = v;
        }
        __syncthreads();
        #pragma unroll
        for (int kk = 0; kk < BK; ++kk) {
            float4 a0 = *(const float4*)&xsT[kk][ty * 8];
            float4 a1 = *(const float4*)&xsT[kk][ty * 8 + 4];
            float4 b = *(const float4*)&ws[kk][tx * 4];
            float av[8] = {a0.x, a0.y, a0.z, a0.w, a1.x, a1.y, a1.z, a1.w};
            float bv[4] = {b.x, b.y, b.z, b.w};
            #pragma unroll
            for (int i = 0; i < 8; ++i) {
                #pragma unroll
                for (int j = 0; j < 4; ++j) acc[i][j] = fmaf(av[i], bv[j], acc[i][j]);
            }
        }
        __syncthreads();
    }
    #pragma unroll
    for (int i = 0; i < 8; ++i) {
        int gr = r0 + ty * 8 + i;
        if (gr < n) {
            float sc = scale[gr];
            ushort4 o;
            o.x = f2bf(acc[i][0] * sc);
            o.y = f2bf(acc[i][1] * sc);
            o.z = f2bf(acc[i][2] * sc);
            o.w = f2bf(acc[i][3] * sc);
            *(ushort4*)&H[(size_t)gr * OUT + tx * 4] = o;
        }
    }
}

// ---------------- aggregation conv1: 64 feats, wave per node, bf16 out ----------------
__global__ __launch_bounds__(256) void agg1_kernel(const int2* __restrict__ csr,
                                                   const int* __restrict__ off,
                                                   const int* __restrict__ cnt,
                                                   const float* __restrict__ dinv,
                                                   const unsigned short* __restrict__ h1t,
                                                   const float* __restrict__ b1,
                                                   unsigned short* __restrict__ h1p) {
    int lane = threadIdx.x & 63;
    int node = blockIdx.x * 4 + (threadIdx.x >> 6);
    int es = lane >> 3;   // edge slot 0..7
    int fb = lane & 7;    // feat block 0..7 (8 feats each)
    int s = off[node], c = cnt[node];
    float acc[8] = {};
    for (int j0 = 0; j0 < c; j0 += 64) {
        int m = min(64, c - j0);
        int2 e = make_int2(0, 0);
        if (lane < m) e = csr[s + j0 + lane];
        int ng = (m + 7) >> 3;
        int g = 0;
        for (; g + 2 <= ng; g += 2) {
            int s0 = g * 8 + es;
            int s1 = s0 + 8;
            int r0 = __shfl(e.x, s0);
            float w0 = __int_as_float(__shfl(e.y, s0));
            int r1 = __shfl(e.x, s1);
            float w1 = __int_as_float(__shfl(e.y, s1));
            int4 d0 = *(const int4*)(h1t + (((size_t)r0) << 6) + (fb << 3));
            int4 d1 = *(const int4*)(h1t + (((size_t)r1) << 6) + (fb << 3));
            acc[0] = fmaf(w0, bfl(d0.x), acc[0]);
            acc[1] = fmaf(w0, bfh(d0.x), acc[1]);
            acc[2] = fmaf(w0, bfl(d0.y), acc[2]);
            acc[3] = fmaf(w0, bfh(d0.y), acc[3]);
            acc[4] = fmaf(w0, bfl(d0.z), acc[4]);
            acc[5] = fmaf(w0, bfh(d0.z), acc[5]);
            acc[6] = fmaf(w0, bfl(d0.w), acc[6]);
            acc[7] = fmaf(w0, bfh(d0.w), acc[7]);
            acc[0] = fmaf(w1, bfl(d1.x), acc[0]);
            acc[1] = fmaf(w1, bfh(d1.x), acc[1]);
            acc[2] = fmaf(w1, bfl(d1.y), acc[2]);
            acc[3] = fmaf(w1, bfh(d1.y), acc[3]);
            acc[4] = fmaf(w1, bfl(d1.z), acc[4]);
            acc[5] = fmaf(w1, bfh(d1.z), acc[5]);
            acc[6] = fmaf(w1, bfl(d1.w), acc[6]);
            acc[7] = fmaf(w1, bfh(d1.w), acc[7]);
        }
        if (g < ng) {
            int s0 = g * 8 + es;
            int r0 = __shfl(e.x, s0);
            float w0 = __int_as_float(__shfl(e.y, s0));
            int4 d0 = *(const int4*)(h1t + (((size_t)r0) << 6) + (fb << 3));
            acc[0] = fmaf(w0, bfl(d0.x), acc[0]);
            acc[1] = fmaf(w0, bfh(d0.x), acc[1]);
            acc[2] = fmaf(w0, bfl(d0.y), acc[2]);
            acc[3] = fmaf(w0, bfh(d0.y), acc[3]);
            acc[4] = fmaf(w0, bfl(d0.z), acc[4]);
            acc[5] = fmaf(w0, bfh(d0.z), acc[5]);
            acc[6] = fmaf(w0, bfl(d0.w), acc[6]);
            acc[7] = fmaf(w0, bfh(d0.w), acc[7]);
        }
    }
    #pragma unroll
    for (int mask = 8; mask <= 32; mask <<= 1) {
        #pragma unroll
        for (int k = 0; k < 8; ++k) acc[k] += __shfl_xor(acc[k], mask);
    }
    if (es == 0) {  // lanes 0..7; fb == lane
        float di = dinv[node];
        int4 ds = *(const int4*)(h1t + (((size_t)node) << 6) + (fb << 3));
        float4 bv0 = *(const float4*)&b1[fb * 8];
        float4 bv1 = *(const float4*)&b1[fb * 8 + 4];
        float v0 = fmaxf(fmaf(acc[0] + bfl(ds.x), di, bv0.x), 0.f);
        float v1 = fmaxf(fmaf(acc[1] + bfh(ds.x), di, bv0.y), 0.f);
        float v2 = fmaxf(fmaf(acc[2] + bfl(ds.y), di, bv0.z), 0.f);
        float v3 = fmaxf(fmaf(acc[3] + bfh(ds.y), di, bv0.w), 0.f);
        float v4 = fmaxf(fmaf(acc[4] + bfl(ds.z), di, bv1.x), 0.f);
        float v5 = fmaxf(fmaf(acc[5] + bfh(ds.z), di, bv1.y), 0.f);
        float v6 = fmaxf(fmaf(acc[6] + bfl(ds.w), di, bv1.z), 0.f);
        float v7 = fmaxf(fmaf(acc[7] + bfh(ds.w), di, bv1.w), 0.f);
        int4 o;
        o.x = (int)pack2bf(v0, v1);
        o.y = (int)pack2bf(v2, v3);
        o.z = (int)pack2bf(v4, v5);
        o.w = (int)pack2bf(v6, v7);
        *(int4*)(h1p + (size_t)node * 64 + fb * 8) = o;
    }
}

// ---------------- aggregation conv2: 32 feats, half-wave per node ----------------
__global__ __launch_bounds__(256) void agg2_kernel(const int2* __restrict__ csr,
                                                   const int* __restrict__ off,
                                                   const int* __restrict__ cnt,
                                                   const float* __restrict__ dinv,
                                                   const unsigned short* __restrict__ h2t,
                                                   const float* __restrict__ b2,
                                                   float* __restrict__ h2p) {
    int lane = threadIdx.x & 63;
    int half = lane >> 5;
    int hl = lane & 31;
    int es = hl >> 2;   // edge slot 0..7
    int fb = hl & 3;    // feat block 0..3 (8 feats each)
    int wid = threadIdx.x >> 6;
    int node = blockIdx.x * 8 + wid * 2 + half;
    int s = off[node], c = cnt[node];
    int lbase = half << 5;
    float acc[8] = {};
    for (int j0 = 0; j0 < c; j0 += 32) {
        int m = min(32, c - j0);
        int2 e = make_int2(0, 0);
        if (hl < m) e = csr[s + j0 + hl];
        int ng = (m + 7) >> 3;
        int g = 0;
        for (; g + 2 <= ng; g += 2) {
            int s0 = lbase + g * 8 + es;
            int s1 = s0 + 8;
            int r0 = __shfl(e.x, s0);
            float w0 = __int_as_float(__shfl(e.y, s0));
            int r1 = __shfl(e.x, s1);
            float w1 = __int_as_float(__shfl(e.y, s1));
            int4 d0 = *(const int4*)(h2t + (((size_t)r0) << 5) + (fb << 3));
            int4 d1 = *(const int4*)(h2t + (((size_t)r1) << 5) + (fb << 3));
            acc[0] = fmaf(w0, bfl(d0.x), acc[0]);
            acc[1] = fmaf(w0, bfh(d0.x), acc[1]);
            acc[2] = fmaf(w0, bfl(d0.y), acc[2]);
            acc[3] = fmaf(w0, bfh(d0.y), acc[3]);
            acc[4] = fmaf(w0, bfl(d0.z), acc[4]);
            acc[5] = fmaf(w0, bfh(d0.z), acc[5]);
            acc[6] = fmaf(w0, bfl(d0.w), acc[6]);
            acc[7] = fmaf(w0, bfh(d0.w), acc[7]);
            acc[0] = fmaf(w1, bfl(d1.x), acc[0]);
            acc[1] = fmaf(w1, bfh(d1.x), acc[1]);
            acc[2] = fmaf(w1, bfl(d1.y), acc[2]);
            acc[3] = fmaf(w1, bfh(d1.y), acc[3]);
            acc[4] = fmaf(w1, bfl(d1.z), acc[4]);
            acc[5] = fmaf(w1, bfh(d1.z), acc[5]);
            acc[6] = fmaf(w1, bfl(d1.w), acc[6]);
            acc[7] = fmaf(w1, bfh(d1.w), acc[7]);
        }
        if (g < ng) {
            int s0 = lbase + g * 8 + es;
            int r0 = __shfl(e.x, s0);
            float w0 = __int_as_float(__shfl(e.y, s0));
            int4 d0 = *(const int4*)(h2t + (((size_t)r0) << 5) + (fb << 3));
            acc[0] = fmaf(w0, bfl(d0.x), acc[0]);
            acc[1] = fmaf(w0, bfh(d0.x), acc[1]);
            acc[2] = fmaf(w0, bfl(d0.y), acc[2]);
            acc[3] = fmaf(w0, bfh(d0.y), acc[3]);
            acc[4] = fmaf(w0, bfl(d0.z), acc[4]);
            acc[5] = fmaf(w0, bfh(d0.z), acc[5]);
            acc[6] = fmaf(w0, bfl(d0.w), acc[6]);
            acc[7] = fmaf(w0, bfh(d0.w), acc[7]);
        }
    }
    #pragma unroll
    for (int mask = 4; mask <= 16; mask <<= 1) {
        #pragma unroll
        for (int k = 0; k < 8; ++k) acc[k] += __shfl_xor(acc[k], mask);
    }
    if (es == 0) {  // hl 0..3; fb == hl
        float di = dinv[node];
        int4 ds = *(const int4*)(h2t + (((size_t)node) << 5) + (fb << 3));
        float4 bv0 = *(const float4*)&b2[fb * 8];
        float4 bv1 = *(const float4*)&b2[fb * 8 + 4];
        float4 o0, o1;
        o0.x = fmaf(acc[0] + bfl(ds.x), di, bv0.x);
        o0.y = fmaf(acc[1] + bfh(ds.x), di, bv0.y);
        o0.z = fmaf(acc[2] + bfl(ds.y), di, bv0.z);
        o0.w = fmaf(acc[3] + bfh(ds.y), di, bv0.w);
        o1.x = fmaf(acc[4] + bfl(ds.z), di, bv1.x);
        o1.y = fmaf(acc[5] + bfh(ds.z), di, bv1.y);
        o1.z = fmaf(acc[6] + bfl(ds.w), di, bv1.z);
        o1.w = fmaf(acc[7] + bfh(ds.w), di, bv1.w);
        float* po = h2p + (size_t)node * 32 + fb * 8;
        *(float4*)po = o0;
        *(float4*)(po + 4) = o1;
    }
}

// ---------------- fused pool + MLP head: one block per graph ----------------
__global__ __launch_bounds__(256) void pool_head_kernel(const float* __restrict__ h2p,
                                                        const int* __restrict__ batch,
                                                        const float* __restrict__ Wl1,
                                                        const float* __restrict__ bl1,
                                                        const float* __restrict__ Wl2,
                                                        const float* __restrict__ bl2,
                                                        float* __restrict__ out) {
    int g = blockIdx.x;
    int lo = 0, hi = N_NODES;
    while (lo < hi) { int m = (lo + hi) >> 1; if (batch[m] < g) lo = m + 1; else hi = m; }
    int start = lo;
    hi = N_NODES;
    while (lo < hi) { int m = (lo + hi) >> 1; if (batch[m] < g + 1) lo = m + 1; else hi = m; }
    int end = lo;
    int f = threadIdx.x & 31, grp = threadIdx.x >> 5;
    float acc = 0.f;
    for (int n = start + grp; n < end; n += 8) acc += h2p[(size_t)n * 32 + f];
    __shared__ float red[8][32];
    __shared__ float usum[32];
    red[grp][f] = acc;
    __syncthreads();
    if (threadIdx.x < 32) {
        float sum = 0.f;
        #pragma unroll
        for (int k = 0; k < 8; ++k) sum += red[k][threadIdx.x];
        usum[threadIdx.x] = sum;
    }
    __syncthreads();
    if (threadIdx.x < 16) {
        int j = threadIdx.x;
        float h = bl1[j];
        #pragma unroll
        for (int k = 0; k < 32; ++k) h = fmaf(usum[k], Wl1[k * 16 + j], h);
        float t = fmaxf(h, 0.f) * Wl2[j];
        t += __shfl_xor(t, 1);
        t += __shfl_xor(t, 2);
        t += __shfl_xor(t, 4);
        t += __shfl_xor(t, 8);
        if (j == 0) out[g] = t + bl2[0];
    }
}

extern "C" void kernel_launch(void* const* d_in, const int* in_sizes, int n_in,
                              void* d_out, int out_size, void* d_ws, size_t ws_size,
                              hipStream_t stream) {
    const float* x     = (const float*)d_in[0];
    const int*   ei    = (const int*)d_in[1];
    const float* ew    = (const float*)d_in[2];
    const int*   batch = (const int*)d_in[3];
    const float* W1    = (const float*)d_in[4];
    const float* b1    = (const float*)d_in[5];
    const float* W2    = (const float*)d_in[6];
    const float* b2    = (const float*)d_in[7];
    const float* Wl1   = (const float*)d_in[8];
    const float* bl1   = (const float*)d_in[9];
    const float* Wl2   = (const float*)d_in[10];
    const float* bl2   = (const float*)d_in[11];
    float* out = (float*)d_out;

    const int* row = ei;
    const int* col = ei + N_EDGES;

    char* p = (char*)d_ws;
    auto alloc = [&](size_t bytes) {
        char* q = p;
        p += (bytes + 255) & ~(size_t)255;
        return q;
    };
    int*   hist   = (int*)alloc((size_t)HIST_N * 4);
    int*   bsum   = (int*)alloc(1024 * 4);
    int2*  rw2    = (int2*)alloc((size_t)N_EDGES * 8);
    int*   off    = (int*)alloc(N_NODES * 4);
    int*   cnt    = (int*)alloc(N_NODES * 4);
    float* dinv   = (float*)alloc(N_NODES * 4);
    int2*  csr    = (int2*)alloc((size_t)N_EDGES * 8);
    unsigned short* h1t = (unsigned short*)rw2;  // alias: rw2 dead after build
    unsigned short* h1p = (unsigned short*)alloc((size_t)N_NODES * 64 * 2);
    unsigned short* h2t = (unsigned short*)alloc((size_t)N_NODES * 32 * 2);
    float* h2p    = (float*)alloc((size_t)N_NODES * 32 * 4);

    const int nbScan = (HIST_N + 4095) / 4096;  // 38

    hist_kernel<<<NB_SORT, 512, 0, stream>>>(col, hist);
    scanA_kernel<<<nbScan, 256, 0, stream>>>(hist, bsum, HIST_N);
    scanB_kernel<<<1, 256, 0, stream>>>(bsum, nbScan);
    scatter_sort_kernel<<<NB_SORT, 512, 0, stream>>>(col, row, ew, hist, bsum, rw2);
    build_kernel<<<NBUCK, 512, 0, stream>>>(hist, bsum, rw2, off, cnt, dinv, csr);

    gemm_bf16_kernel<128, 64, 128><<<(N_NODES + 127) / 128, 256, 0, stream>>>(x, W1, dinv, h1t, N_NODES);
    agg1_kernel<<<N_NODES / 4, 256, 0, stream>>>(csr, off, cnt, dinv, h1t, b1, h1p);
    gemm_bf16in_kernel<64, 32, 256><<<(N_NODES + 255) / 256, 256, 0, stream>>>(h1p, W2, dinv, h2t, N_NODES);
    agg2_kernel<<<N_NODES / 8, 256, 0, stream>>>(csr, off, cnt, dinv, h2t, b2, h2p);
    pool_head_kernel<<<N_GRAPHS, 256, 0, stream>>>(h2p, batch, Wl1, bl1, Wl2, bl2, out);
}